// Round 14
// baseline (24.757 us; speedup 1.0000x reference)
//
#include <hip/hip_runtime.h>
#include <cfloat>

// ChamferLossKL: bs=8, n=2048, d=4, fp32 in/out; one-pass pair matrix.
// s_ij = 2*KL(pred_i||gt_j) = dot(pa_i,ivb_j) + dot(mua_i,m2_j) + ca_i + cb_j
//   row (pred) record: pa = exp(lva)+mua^2, mua, ca = -sum(lva)-4   (f32->fp16 packed)
//   col (gt)   record: ivb = exp(-lvb), m2 = -2*mub*ivb, cb (f32)   (fp16 packed)
// loss[b] = 0.5*(sum_i min_j s + sum_j min_i s), both mins of the SAME s.
//
// R10->R11: main was LDS-pipe-bound (36 cy/jj/wave for 256 pairs at RPT=4)
// and VALU floor 11 ops/pair. Pack both operand records as fp16 (inputs only;
// accumulation stays f32 via v_dot2_f32_f16): column record = one half8
// (b128) + f32 cb (b32) -> 26 cy/jj; pair math = 4 fdot2 + add + 2 fmin =
// 7 ops/pair. Row tile drops to ~35 live regs -- far under the ~56-reg
// ceiling the allocator enforces (R4/5/8/9 evidence), so no spill possible.
// Precision: fp16 rounding on inputs only, f32 accum; ca/cb exact f32;
// estimated absmax ~1-5 vs threshold 51.2.

#define TPB     1024
#define WAVES   16
#define RPT     4
#define ROWSPB  (WAVES * RPT)     // 64 rows per block
#define NFIX    2048
#define CH_COLS 1024              // columns per block (z-dim halves)
#define NRG     (NFIX / ROWSPB)   // 32 row groups

typedef _Float16 half_t;
typedef __attribute__((ext_vector_type(2))) _Float16 half2_t;
typedef __attribute__((ext_vector_type(8))) _Float16 half8_t;

__device__ __forceinline__ float dot2acc(half2_t a, half2_t b, float c) {
#if __has_builtin(__builtin_amdgcn_fdot2)
    return __builtin_amdgcn_fdot2(a, b, c, false);   // fp16 mul, f32 accum
#else
    return fmaf((float)a[1], (float)b[1], fmaf((float)a[0], (float)b[0], c));
#endif
}

__device__ __forceinline__ unsigned enc_f32(float f) {
    unsigned u = __float_as_uint(f);
    return (u & 0x80000000u) ? ~u : (u | 0x80000000u);
}
__device__ __forceinline__ float dec_f32(unsigned e) {
    return (e & 0x80000000u) ? __uint_as_float(e ^ 0x80000000u)
                             : __uint_as_float(~e);
}

__global__ __launch_bounds__(TPB) void chamfer_kl_main(
    const float4* __restrict__ mu_a, const float4* __restrict__ lv_a,
    const float4* __restrict__ mu_b, const float4* __restrict__ lv_b,
    float* __restrict__ rowpart,     // [8][2][2048]
    float* __restrict__ colpart)     // [8][32][2048]
{
    __shared__ half8_t  sch[CH_COLS];   // ivb(4h), m2(4h)  16 KB
    __shared__ float    scb[CH_COLS];   // cb                4 KB
    __shared__ unsigned scm[CH_COLS];   // enc col-min       4 KB

    const int t    = threadIdx.x;
    const int rg   = blockIdx.x;     // 32 row groups
    const int b    = blockIdx.y;     // 8 batches
    const int ch   = blockIdx.z;     // 2 column halves
    const int lane = t & 63;
    const int wid  = t >> 6;
    const int n    = NFIX;

    // ---- stage this half's column records (gts -> B-type), 1 per thread
    {
        const int j = ch * CH_COLS + t;
        float4 mu = mu_b[(size_t)b * n + j];
        float4 lv = lv_b[(size_t)b * n + j];
        float ivx = __expf(-lv.x), ivy = __expf(-lv.y);
        float ivz = __expf(-lv.z), ivw = __expf(-lv.w);
        half8_t h;
        h[0] = (half_t)ivx;               h[1] = (half_t)ivy;
        h[2] = (half_t)ivz;               h[3] = (half_t)ivw;
        h[4] = (half_t)(-2.f * mu.x * ivx); h[5] = (half_t)(-2.f * mu.y * ivy);
        h[6] = (half_t)(-2.f * mu.z * ivz); h[7] = (half_t)(-2.f * mu.w * ivw);
        sch[t] = h;
        scb[t] = mu.x * mu.x * ivx + mu.y * mu.y * ivy
               + mu.z * mu.z * ivz + mu.w * mu.w * ivw
               + lv.x + lv.y + lv.z + lv.w;
        scm[t] = 0xFFFFFFFFu;
    }

    // ---- row records (preds -> A-type), 4 rows/thread, fp16-packed
    const int rbase = rg * ROWSPB + wid * RPT;
    half2_t rp0[RPT], rp1[RPT];   // pa pairs
    half2_t rq0[RPT], rq1[RPT];   // mua pairs
    float   rc[RPT], rmin[RPT];
#pragma unroll
    for (int r = 0; r < RPT; ++r) {
        float4 mu = mu_a[(size_t)b * n + rbase + r];
        float4 lv = lv_a[(size_t)b * n + rbase + r];
        float pax = __expf(lv.x) + mu.x * mu.x;
        float pay = __expf(lv.y) + mu.y * mu.y;
        float paz = __expf(lv.z) + mu.z * mu.z;
        float paw = __expf(lv.w) + mu.w * mu.w;
        rp0[r][0] = (half_t)pax;  rp0[r][1] = (half_t)pay;
        rp1[r][0] = (half_t)paz;  rp1[r][1] = (half_t)paw;
        rq0[r][0] = (half_t)mu.x; rq0[r][1] = (half_t)mu.y;
        rq1[r][0] = (half_t)mu.z; rq1[r][1] = (half_t)mu.w;
        rc[r]   = -(lv.x + lv.y + lv.z + lv.w) - 4.f;
        rmin[r] = FLT_MAX;
    }
    __syncthreads();

    // ---- main sweep: 64 rows x 1024 cols, each pair once, s = 2*KL
    for (int jj = 0; jj < CH_COLS / 64; ++jj) {
        const int j = (jj << 6) + lane;
        const half8_t hc = sch[j];                 // one ds_read_b128
        half2_t c01 = { hc[0], hc[1] };
        half2_t c23 = { hc[2], hc[3] };
        half2_t d01 = { hc[4], hc[5] };
        half2_t d23 = { hc[6], hc[7] };
        const float cb = scb[j];
        float cmin = FLT_MAX;
#pragma unroll
        for (int r = 0; r < RPT; ++r) {
            float s = dot2acc(rp0[r], c01, rc[r]); // seeded with f32 ca_i
            s = dot2acc(rp1[r], c23, s);
            s = dot2acc(rq0[r], d01, s);
            s = dot2acc(rq1[r], d23, s);
            s += cb;                               // s = 2*KL(i,j)
            rmin[r] = fminf(rmin[r], s);
            cmin    = fminf(cmin, s);
        }
        atomicMin(&scm[j], enc_f32(cmin));         // ds_min_u32
    }
    __syncthreads();

    // ---- col partials for this row group (coalesced stores)
    colpart[((size_t)b * NRG + rg) * n + ch * CH_COLS + t] = dec_f32(scm[t]);

    // ---- row partials: min across 64 lanes per row
    float* rp = rowpart + ((size_t)b * 2 + ch) * n + rbase;
#pragma unroll
    for (int r = 0; r < RPT; ++r) {
        float m = rmin[r];
#pragma unroll
        for (int off = 32; off; off >>= 1)
            m = fminf(m, __shfl_xor(m, off, 64));
        if (lane == 0) rp[r] = m;
    }
}

// One block per batch: sum col-mins (min over 32 row groups) plus sum of
// row-mins (min over 2 column halves). Kernel boundary = barrier+visibility;
// out[] is overwritten (poison-safe, deterministic).
__global__ __launch_bounds__(TPB) void chamfer_kl_reduce(
    const float* __restrict__ rowpart,   // [8][2][2048]
    const float* __restrict__ colpart,   // [8][32][2048]
    float* __restrict__ out)
{
    __shared__ float fsum[WAVES];
    const int t    = threadIdx.x;
    const int b    = blockIdx.x;
    const int lane = t & 63;
    const int wid  = t >> 6;
    const int n    = NFIX;

    float acc = 0.f;
#pragma unroll
    for (int it = 0; it < NFIX / TPB; ++it) {   // 2 iterations
        const int j = it * TPB + t;
        float m = colpart[((size_t)b * NRG + 0) * n + j];
#pragma unroll
        for (int g = 1; g < NRG; ++g)
            m = fminf(m, colpart[((size_t)b * NRG + g) * n + j]);
        acc += m;
        acc += fminf(rowpart[((size_t)b * 2 + 0) * n + j],
                     rowpart[((size_t)b * 2 + 1) * n + j]);
    }
#pragma unroll
    for (int off = 32; off; off >>= 1) acc += __shfl_xor(acc, off, 64);
    if (lane == 0) fsum[wid] = acc;
    __syncthreads();
    if (wid == 0) {
        float v = (lane < WAVES) ? fsum[lane] : 0.f;
#pragma unroll
        for (int off = 8; off; off >>= 1) v += __shfl_xor(v, off, 64);
        if (t == 0) out[b] = 0.5f * v;
    }
}

extern "C" void kernel_launch(void* const* d_in, const int* in_sizes, int n_in,
                              void* d_out, int out_size, void* d_ws, size_t ws_size,
                              hipStream_t stream) {
    const float4* mu_a = (const float4*)d_in[0];  // mu_preds
    const float4* lv_a = (const float4*)d_in[1];  // logvar_preds
    const float4* mu_b = (const float4*)d_in[2];  // mu_gts
    const float4* lv_b = (const float4*)d_in[3];  // logvar_gts

    const int bs = out_size;  // 8

    float* ws = (float*)d_ws;
    float* colpart = ws;                              // 8*32*2048 floats (2 MB)
    float* rowpart = ws + (size_t)bs * NRG * NFIX;    // 8*2*2048 floats

    dim3 grid(NRG, bs, 2);  // (32, 8, 2) = 512 blocks = 2/CU
    chamfer_kl_main<<<grid, TPB, 0, stream>>>(mu_a, lv_a, mu_b, lv_b,
                                              rowpart, colpart);
    chamfer_kl_reduce<<<bs, TPB, 0, stream>>>(rowpart, colpart, (float*)d_out);
}

// Round 15
// 22.819 us; speedup vs baseline: 1.0850x; 1.0850x over previous
//
#include <hip/hip_runtime.h>
#include <cfloat>

// ChamferLossKL: bs=8, n=2048, d=4, fp32 in/out; one-pass pair matrix.
// s_ij = 2*KL(pred_i||gt_j) = dot(pa_i,ivb_j) + dot(mua_i,m2_j) + ca_i + cb_j
//   row (pred) record: pa = exp(lva)+mua^2, mua, ca = -sum(lva)-4  (fp16 packed)
//   col (gt)   record: ivb = exp(-lvb), m2 = -2*mub*ivb (fp16), cb (f32)
// loss[b] = 0.5*(sum_i min_j s + sum_j min_i s), both mins of the SAME s.
//
// R11->R15: LDS-pipe model explains the plateau. Per-CU LDS cycles scale
// with (waves/CU)*jj: R7 (RPT=8, 1 blk/CU, 16 jj, fp32) ~3.8us -> VALU-bound
// main 6-7us; R10/R11 (RPT=4, 2 blk/CU, 32 jj) ~10-14us -> LDS-bound. RPT=8
// is right; R7 just got allocator luck with its 80-reg f32 tile. fp16-packed
// rows at RPT=8 need ~60 live regs -- fits even the 64-VGPR budget the
// backend pins (R4/5/8/9 evidence: always 56-64). Geometry = R7's:
// 256 blocks, 1/CU, 16 jj; LDS/jj/wave = b128+b32+ds_atomic ~24cy -> 2.6us;
// VALU 7 ops/pair -> ~3us; main ~4-5us. Two-kernel structure kept.

#define TPB     1024
#define WAVES   16
#define RPT     8
#define ROWSPB  (WAVES * RPT)     // 128 rows per block
#define NFIX    2048
#define CH_COLS 1024              // columns per block (z-dim halves)
#define NRG     (NFIX / ROWSPB)   // 16 row groups

typedef _Float16 half_t;
typedef __attribute__((ext_vector_type(2))) _Float16 half2_t;
typedef __attribute__((ext_vector_type(8))) _Float16 half8_t;

__device__ __forceinline__ float dot2acc(half2_t a, half2_t b, float c) {
#if __has_builtin(__builtin_amdgcn_fdot2)
    return __builtin_amdgcn_fdot2(a, b, c, false);   // fp16 mul, f32 accum
#else
    return fmaf((float)a[1], (float)b[1], fmaf((float)a[0], (float)b[0], c));
#endif
}

__device__ __forceinline__ unsigned enc_f32(float f) {
    unsigned u = __float_as_uint(f);
    return (u & 0x80000000u) ? ~u : (u | 0x80000000u);
}
__device__ __forceinline__ float dec_f32(unsigned e) {
    return (e & 0x80000000u) ? __uint_as_float(e ^ 0x80000000u)
                             : __uint_as_float(~e);
}

__global__ __launch_bounds__(TPB) void chamfer_kl_main(
    const float4* __restrict__ mu_a, const float4* __restrict__ lv_a,
    const float4* __restrict__ mu_b, const float4* __restrict__ lv_b,
    float* __restrict__ rowpart,     // [8][2][2048]
    float* __restrict__ colpart)     // [8][16][2048]
{
    __shared__ half8_t  sch[CH_COLS];   // ivb(4h), m2(4h)  16 KB
    __shared__ float    scb[CH_COLS];   // cb                4 KB
    __shared__ unsigned scm[CH_COLS];   // enc col-min       4 KB

    const int t    = threadIdx.x;
    const int rg   = blockIdx.x;     // 16 row groups
    const int b    = blockIdx.y;     // 8 batches
    const int ch   = blockIdx.z;     // 2 column halves
    const int lane = t & 63;
    const int wid  = t >> 6;
    const int n    = NFIX;

    // ---- stage this half's column records (gts -> B-type), 1 per thread
    {
        const int j = ch * CH_COLS + t;
        float4 mu = mu_b[(size_t)b * n + j];
        float4 lv = lv_b[(size_t)b * n + j];
        float ivx = __expf(-lv.x), ivy = __expf(-lv.y);
        float ivz = __expf(-lv.z), ivw = __expf(-lv.w);
        half8_t h;
        h[0] = (half_t)ivx;                 h[1] = (half_t)ivy;
        h[2] = (half_t)ivz;                 h[3] = (half_t)ivw;
        h[4] = (half_t)(-2.f * mu.x * ivx); h[5] = (half_t)(-2.f * mu.y * ivy);
        h[6] = (half_t)(-2.f * mu.z * ivz); h[7] = (half_t)(-2.f * mu.w * ivw);
        sch[t] = h;
        scb[t] = mu.x * mu.x * ivx + mu.y * mu.y * ivy
               + mu.z * mu.z * ivz + mu.w * mu.w * ivw
               + lv.x + lv.y + lv.z + lv.w;
        scm[t] = 0xFFFFFFFFu;
    }

    // ---- row records (preds -> A-type), 8 rows/thread, fp16-packed
    //      (4 dwords/row -> 32 VGPRs operands + 16 rc/rmin ~= 60 live: fits
    //       the 64-VGPR budget the backend enforces, no spill possible)
    const int rbase = rg * ROWSPB + wid * RPT;
    half2_t rp0[RPT], rp1[RPT];   // pa pairs
    half2_t rq0[RPT], rq1[RPT];   // mua pairs
    float   rc[RPT], rmin[RPT];
#pragma unroll
    for (int r = 0; r < RPT; ++r) {
        float4 mu = mu_a[(size_t)b * n + rbase + r];
        float4 lv = lv_a[(size_t)b * n + rbase + r];
        rp0[r][0] = (half_t)(__expf(lv.x) + mu.x * mu.x);
        rp0[r][1] = (half_t)(__expf(lv.y) + mu.y * mu.y);
        rp1[r][0] = (half_t)(__expf(lv.z) + mu.z * mu.z);
        rp1[r][1] = (half_t)(__expf(lv.w) + mu.w * mu.w);
        rq0[r][0] = (half_t)mu.x; rq0[r][1] = (half_t)mu.y;
        rq1[r][0] = (half_t)mu.z; rq1[r][1] = (half_t)mu.w;
        rc[r]   = -(lv.x + lv.y + lv.z + lv.w) - 4.f;
        rmin[r] = FLT_MAX;
    }
    __syncthreads();

    // ---- main sweep: 128 rows x 1024 cols, each pair once, s = 2*KL
    for (int jj = 0; jj < CH_COLS / 64; ++jj) {     // 16 iterations
        const int j = (jj << 6) + lane;
        const half8_t hc = sch[j];                  // one ds_read_b128
        half2_t c01 = { hc[0], hc[1] };
        half2_t c23 = { hc[2], hc[3] };
        half2_t d01 = { hc[4], hc[5] };
        half2_t d23 = { hc[6], hc[7] };
        const float cb = scb[j];
        float cmin = FLT_MAX;
#pragma unroll
        for (int r = 0; r < RPT; ++r) {
            float s = dot2acc(rp0[r], c01, rc[r]);  // seeded with f32 ca_i
            s = dot2acc(rp1[r], c23, s);
            s = dot2acc(rq0[r], d01, s);
            s = dot2acc(rq1[r], d23, s);
            s += cb;                                // s = 2*KL(i,j)
            rmin[r] = fminf(rmin[r], s);
            cmin    = fminf(cmin, s);
        }
        atomicMin(&scm[j], enc_f32(cmin));          // ds_min_u32
    }
    __syncthreads();

    // ---- col partials for this row group (coalesced stores)
    colpart[((size_t)b * NRG + rg) * n + ch * CH_COLS + t] = dec_f32(scm[t]);

    // ---- row partials: min across 64 lanes per row
    float* rp = rowpart + ((size_t)b * 2 + ch) * n + rbase;
#pragma unroll
    for (int r = 0; r < RPT; ++r) {
        float m = rmin[r];
#pragma unroll
        for (int off = 32; off; off >>= 1)
            m = fminf(m, __shfl_xor(m, off, 64));
        if (lane == 0) rp[r] = m;
    }
}

// One block per batch: sum col-mins (min over 16 row groups) plus sum of
// row-mins (min over 2 column halves). Kernel boundary = barrier+visibility;
// out[] is overwritten (poison-safe, deterministic).
__global__ __launch_bounds__(TPB) void chamfer_kl_reduce(
    const float* __restrict__ rowpart,   // [8][2][2048]
    const float* __restrict__ colpart,   // [8][16][2048]
    float* __restrict__ out)
{
    __shared__ float fsum[WAVES];
    const int t    = threadIdx.x;
    const int b    = blockIdx.x;
    const int lane = t & 63;
    const int wid  = t >> 6;
    const int n    = NFIX;

    float acc = 0.f;
#pragma unroll
    for (int it = 0; it < NFIX / TPB; ++it) {   // 2 iterations
        const int j = it * TPB + t;
        float m = colpart[((size_t)b * NRG + 0) * n + j];
#pragma unroll
        for (int g = 1; g < NRG; ++g)
            m = fminf(m, colpart[((size_t)b * NRG + g) * n + j]);
        acc += m;
        acc += fminf(rowpart[((size_t)b * 2 + 0) * n + j],
                     rowpart[((size_t)b * 2 + 1) * n + j]);
    }
#pragma unroll
    for (int off = 32; off; off >>= 1) acc += __shfl_xor(acc, off, 64);
    if (lane == 0) fsum[wid] = acc;
    __syncthreads();
    if (wid == 0) {
        float v = (lane < WAVES) ? fsum[lane] : 0.f;
#pragma unroll
        for (int off = 8; off; off >>= 1) v += __shfl_xor(v, off, 64);
        if (t == 0) out[b] = 0.5f * v;
    }
}

extern "C" void kernel_launch(void* const* d_in, const int* in_sizes, int n_in,
                              void* d_out, int out_size, void* d_ws, size_t ws_size,
                              hipStream_t stream) {
    const float4* mu_a = (const float4*)d_in[0];  // mu_preds
    const float4* lv_a = (const float4*)d_in[1];  // logvar_preds
    const float4* mu_b = (const float4*)d_in[2];  // mu_gts
    const float4* lv_b = (const float4*)d_in[3];  // logvar_gts

    const int bs = out_size;  // 8

    float* ws = (float*)d_ws;
    float* colpart = ws;                              // 8*16*2048 floats (1 MB)
    float* rowpart = ws + (size_t)bs * NRG * NFIX;    // 8*2*2048 floats

    dim3 grid(NRG, bs, 2);  // (16, 8, 2) = 256 blocks = 1/CU
    chamfer_kl_main<<<grid, TPB, 0, stream>>>(mu_a, lv_a, mu_b, lv_b,
                                              rowpart, colpart);
    chamfer_kl_reduce<<<bs, TPB, 0, stream>>>(rowpart, colpart, (float*)d_out);
}